// Round 4
// baseline (165.575 us; speedup 1.0000x reference)
//
#include <hip/hip_runtime.h>
#include <hip/hip_bf16.h>
#include <math.h>

#define NEGF (-1e30f)
#define LOG2E 1.4426950408889634f
#define LN2F 0.6931471805599453f
#define TSCALE 2.885390081777927f     // 2*log2(e), folded into f and g

typedef __attribute__((ext_vector_type(8))) short bf16x8;
typedef __attribute__((ext_vector_type(4))) float f32x4;

#define DROWS_PAD 480        // diagonals 0..459 used; padded for static prefetch
#define DPITCH 64
#define PF 16                // prefetch depth (rows)

__device__ __forceinline__ unsigned short f2bf(float x) {
    __hip_bfloat16 h = __float2bfloat16(x);
    return *reinterpret_cast<unsigned short*>(&h);
}

__device__ __forceinline__ float wave_shr1(float x) {
    int i = __builtin_bit_cast(int, x);
    int r = __builtin_amdgcn_update_dpp(0, i, 0x138, 0xf, 0xf, true); // wf_shr:1
    return __builtin_bit_cast(float, r);
}

// reciprocal via bit-hack + 1 Newton step: pure VALU (no trans pipe).
__device__ __forceinline__ float4 rcp4_nr(float4 d) {
    float4 y;
    y.x = __builtin_bit_cast(float, 0x7EF311C3 - __builtin_bit_cast(int, d.x));
    y.y = __builtin_bit_cast(float, 0x7EF311C3 - __builtin_bit_cast(int, d.y));
    y.z = __builtin_bit_cast(float, 0x7EF311C3 - __builtin_bit_cast(int, d.z));
    y.w = __builtin_bit_cast(float, 0x7EF311C3 - __builtin_bit_cast(int, d.w));
    float4 t;
    t.x = fmaf(-d.x, y.x, 2.f); t.y = fmaf(-d.y, y.y, 2.f);
    t.z = fmaf(-d.z, y.z, 2.f); t.w = fmaf(-d.w, y.w, 2.f);
    y.x *= t.x; y.y *= t.y; y.z *= t.z; y.w *= t.w;
    return y;
}

// ---------------------------------------------------------------------------
// Kernel 0 (pack): bf16 B-fragments for We (16384 entries), Wd (16384),
// and -2*Wp (2048, sigmoid form); plus csbp[v] = colsum(Wp)[v] + bp[v].
// ---------------------------------------------------------------------------
__global__ __launch_bounds__(256) void k_pack(const float* __restrict__ We,
                                              const float* __restrict__ Wd,
                                              const float* __restrict__ Wp,
                                              const float* __restrict__ bp,
                                              unsigned short* __restrict__ WeFrag,
                                              unsigned short* __restrict__ WdFrag,
                                              unsigned short* __restrict__ BfragP,
                                              float* __restrict__ csbp) {
    int gid = blockIdx.x * 256 + threadIdx.x;
    if (gid < 32768) {   // We / Wd
        const float* W = (gid < 16384) ? We : Wd;
        unsigned short* F = (gid < 16384) ? WeFrag : WdFrag;
        int s = gid & 16383;
        int lane = s & 63;
        int c = (s >> 6) & 7;
        int nt = s >> 9;
        int n = nt * 16 + (lane & 15);
        int kbase = c * 32 + ((lane >> 4) & 3) * 8;
        unsigned short* dst = F + (size_t)s * 8;
#pragma unroll
        for (int j = 0; j < 8; ++j) dst[j] = f2bf(W[(size_t)(kbase + j) * 512 + n]);
    } else if (gid < 34816) {            // -2*Wp: 2048 entries
        int s = gid - 32768;
        int lane = s & 63;
        int half = (s >> 6) & 1;
        int c = s >> 7;
        int n = half * 16 + (lane & 15);
        int kbase = c * 32 + (lane >> 4) * 8;
        unsigned short* dst = BfragP + (size_t)s * 8;
#pragma unroll
        for (int j = 0; j < 8; ++j) {
            float v = (n < 28) ? (-2.f * Wp[(kbase + j) * 28 + n]) : 0.f;
            dst[j] = f2bf(v);
        }
    } else if (gid < 34848) {            // csbp: 32 entries
        int v = gid - 34816;
        float s = 0.f;
        if (v < 28) {
            for (int k = 0; k < 512; ++k) s += Wp[k * 28 + v];
            s += bp[v];
        }
        csbp[v] = s;
    }
}

// ---------------------------------------------------------------------------
// Kernel 1 (MFMA projections): f = (enc@We)*TSCALE, g = (dec@Wd + bf)*TSCALE.
// ---------------------------------------------------------------------------
__global__ __launch_bounds__(256) void k_gemm(const float* __restrict__ enc,
                                              const float* __restrict__ dec,
                                              const float* __restrict__ bfv,
                                              const unsigned short* __restrict__ WeFrag,
                                              const unsigned short* __restrict__ WdFrag,
                                              float* __restrict__ f,
                                              float* __restrict__ g) {
    const int wid = blockIdx.x * 4 + threadIdx.y;
    const int lane = threadIdx.x;
    const int m16 = lane & 15;
    const int quad = lane >> 4;

    const float* A; const unsigned short* WF; float* Out; int M, rt, ct; bool isg;
    if (wid < 1600) { A = enc; WF = WeFrag; Out = f; M = 3200; rt = wid >> 3; ct = wid & 7; isg = false; }
    else { int w2 = wid - 1600; A = dec; WF = WdFrag; Out = g; M = 488; rt = w2 >> 3; ct = w2 & 7; isg = true; }

    const int row = rt * 16 + m16;
    const float* arow = A + (size_t)min(row, M - 1) * 256 + quad * 8;

    f32x4 acc[4];
#pragma unroll
    for (int i = 0; i < 4; ++i) acc[i] = (f32x4){0.f, 0.f, 0.f, 0.f};

#pragma unroll
    for (int c = 0; c < 8; ++c) {
        float4 a0 = *(const float4*)(arow + c * 32);
        float4 a1 = *(const float4*)(arow + c * 32 + 4);
        union { unsigned short s[8]; bf16x8 v; } Af;
        Af.s[0] = f2bf(a0.x); Af.s[1] = f2bf(a0.y);
        Af.s[2] = f2bf(a0.z); Af.s[3] = f2bf(a0.w);
        Af.s[4] = f2bf(a1.x); Af.s[5] = f2bf(a1.y);
        Af.s[6] = f2bf(a1.z); Af.s[7] = f2bf(a1.w);
#pragma unroll
        for (int i = 0; i < 4; ++i) {
            int nt = ct * 4 + i;
            bf16x8 Bv = *(const bf16x8*)(WF + (size_t)((nt * 8 + c) * 64 + lane) * 8);
            acc[i] = __builtin_amdgcn_mfma_f32_16x16x32_bf16(Af.v, Bv, acc[i], 0, 0, 0);
        }
    }

#pragma unroll
    for (int i = 0; i < 4; ++i) {
        int n = ct * 64 + i * 16 + m16;
        float bv = isg ? bfv[n] : 0.f;
#pragma unroll
        for (int r = 0; r < 4; ++r) {
            int ro = rt * 16 + quad * 4 + r;
            if (ro < M) Out[(size_t)ro * 512 + n] = (acc[i][r] + bv) * TSCALE;
        }
    }
}

// ---------------------------------------------------------------------------
// Kernel 2: per-cell blank/label log-probs (log2 domain).
// Each block stages the 16-row f tile ONCE and serves a u-span of 16
// (4 u-blocks iterated in-register): staging traffic / barrier count /4.
// Depth-1 register double-buffer pipeline per u-iteration (round-3 verified).
// ---------------------------------------------------------------------------
__global__ __launch_bounds__(256, 4) void k_cells(const float* __restrict__ f,
                                                  const float* __restrict__ g,
                                                  const unsigned short* __restrict__ Bfrag,
                                                  const float* __restrict__ csbp,
                                                  const int* __restrict__ targets,
                                                  const int* __restrict__ ilen,
                                                  const int* __restrict__ ulenp,
                                                  float2* __restrict__ pairD) {
    const int b = blockIdx.z;
    const int tlen = ilen[b];
    const int ulen = ulenp[b];
    const int t0 = blockIdx.x * 16;
    if (t0 >= tlen) return;                       // block-uniform exit
    if ((int)blockIdx.y * 16 > ulen) return;      // u-span entirely past ulen
    const int wave = threadIdx.y;
    const int lane = threadIdx.x;
    const int tid = wave * 64 + lane;

    __shared__ float fs[16 * 516];                // stride 516: b128 reads conflict-free

    {   // stage f tile (16 rows x 512), coalesced float4 -- once per block
        const float4* src = (const float4*)(f + (size_t)(b * 400 + t0) * 512);
#pragma unroll
        for (int i = 0; i < 8; ++i) {
            int idx = tid + i * 256;
            int row = idx >> 7;
            int c4 = idx & 127;
            float4 v = src[idx];
            *(float4*)&fs[row * 516 + c4 * 4] = v;
        }
    }
    __syncthreads();

    const int quad = lane >> 4;
    const int m16 = lane & 15;
    const float* fsrow = fs + m16 * 516 + quad * 8;
    const float4 one4 = make_float4(1.f, 1.f, 1.f, 1.f);
    const float cs0 = csbp[m16];
    const int n1 = 16 + m16;
    const bool n1v = (n1 < 28);
    const float cs1 = csbp[n1 & 31];
    float2* Pd = pairD + (size_t)b * (DROWS_PAD * DPITCH);

    for (int ub = 0; ub < 4; ++ub) {
        const int ubase = blockIdx.y * 16 + ub * 4;
        if (ubase > ulen) break;                  // uniform: later u never feeds answer
        const int u_raw = ubase + wave;
        const int u = min(u_raw, 60);
        const float* gu = g + (size_t)(b * 61 + u) * 512 + quad * 8;

        f32x4 acc0 = {0.f, 0.f, 0.f, 0.f};
        f32x4 acc1 = {0.f, 0.f, 0.f, 0.f};

        // depth-1 software pipeline: load iteration c+1 while computing c.
        float4 FA[2], FB[2], GA[2], GB[2];
        bf16x8 BR0[2], BR1[2];
        FA[0] = *(const float4*)(fsrow);
        FB[0] = *(const float4*)(fsrow + 4);
        GA[0] = *(const float4*)(gu);
        GB[0] = *(const float4*)(gu + 4);
        BR0[0] = *(const bf16x8*)(Bfrag + ((size_t)(0 * 64 + lane)) * 8);
        BR1[0] = *(const bf16x8*)(Bfrag + ((size_t)(1 * 64 + lane)) * 8);

#pragma unroll
        for (int c = 0; c < 16; ++c) {
            const int cu = c & 1;            // static after full unroll
            const int nx = cu ^ 1;
            if (c < 15) {
                FA[nx] = *(const float4*)(fsrow + (c + 1) * 32);
                FB[nx] = *(const float4*)(fsrow + (c + 1) * 32 + 4);
                GA[nx] = *(const float4*)(gu + (c + 1) * 32);
                GB[nx] = *(const float4*)(gu + (c + 1) * 32 + 4);
                BR0[nx] = *(const bf16x8*)(Bfrag + ((size_t)(((c + 1) * 2 + 0) * 64 + lane)) * 8);
                BR1[nx] = *(const bf16x8*)(Bfrag + ((size_t)(((c + 1) * 2 + 1) * 64 + lane)) * 8);
            }
            float4 s0 = FA[cu] + GA[cu];              // pk adds (pre-scaled by 2log2e)
            float4 s1 = FB[cu] + GB[cu];
            float4 e0, e1;
            e0.x = __builtin_amdgcn_exp2f(s0.x); e0.y = __builtin_amdgcn_exp2f(s0.y);
            e0.z = __builtin_amdgcn_exp2f(s0.z); e0.w = __builtin_amdgcn_exp2f(s0.w);
            e1.x = __builtin_amdgcn_exp2f(s1.x); e1.y = __builtin_amdgcn_exp2f(s1.y);
            e1.z = __builtin_amdgcn_exp2f(s1.z); e1.w = __builtin_amdgcn_exp2f(s1.w);
            float4 r0 = rcp4_nr(e0 + one4);           // sigma = 1/(1+e), no trans rcp
            float4 r1 = rcp4_nr(e1 + one4);
            union { unsigned short s[8]; bf16x8 v; } A;
            A.s[0] = f2bf(r0.x); A.s[1] = f2bf(r0.y);
            A.s[2] = f2bf(r0.z); A.s[3] = f2bf(r0.w);
            A.s[4] = f2bf(r1.x); A.s[5] = f2bf(r1.y);
            A.s[6] = f2bf(r1.z); A.s[7] = f2bf(r1.w);
            acc0 = __builtin_amdgcn_mfma_f32_16x16x32_bf16(A.v, BR0[cu], acc0, 0, 0, 0);
            acc1 = __builtin_amdgcn_mfma_f32_16x16x32_bf16(A.v, BR1[cu], acc1, 0, 0, 0);
        }

        // epilogue: logits l[v] = csbp[v] + acc  (acc = sum(-2Wp * sigma))
        int tv = targets[b * 60 + min(u, 59)];

        float res_blank[4], res_lab[4];
#pragma unroll
        for (int r = 0; r < 4; ++r) {
            float l0 = acc0[r] + cs0;
            float l1 = n1v ? (acc1[r] + cs1) : NEGF;
            float mx = fmaxf(l0, l1);
            mx = fmaxf(mx, __shfl_xor(mx, 1, 64));
            mx = fmaxf(mx, __shfl_xor(mx, 2, 64));
            mx = fmaxf(mx, __shfl_xor(mx, 4, 64));
            mx = fmaxf(mx, __shfl_xor(mx, 8, 64));
            float s = __builtin_amdgcn_exp2f((l0 - mx) * LOG2E) +
                      __builtin_amdgcn_exp2f((l1 - mx) * LOG2E);
            s += __shfl_xor(s, 1, 64);
            s += __shfl_xor(s, 2, 64);
            s += __shfl_xor(s, 4, 64);
            s += __shfl_xor(s, 8, 64);
            float lse = mx + __logf(s);
            int base = lane & 48;
            float labsrc = (tv < 16) ? l0 : l1;
            float labv = __shfl(labsrc, base | (tv & 15), 64);
            float blankv = __shfl(l1, base | 11, 64);   // v=27 -> half1 local 11
            res_blank[r] = (blankv - lse) * LOG2E;      // log2 domain
            res_lab[r] = (labv - lse) * LOG2E;
        }

        if (m16 == 0 && u_raw <= 60) {
#pragma unroll
            for (int r = 0; r < 4; ++r) {
                int t = t0 + quad * 4 + r;
                if (t < tlen) {
                    int d = t + u;
                    float2 pr;
                    pr.x = res_blank[r];
                    pr.y = (u <= 59) ? res_lab[r] : NEGF;
                    Pd[d * DPITCH + u] = pr;
                }
            }
        }
    }
}

// ---------------------------------------------------------------------------
// Kernel 3: anti-diagonal alpha recursion, one wave per batch.
// DOUBLE-STEP: two diagonals composed into one 3-term LSE --
//   cur'[u] = LSE3(cur[u]+A, cur[u-1]+B, cur[u-2]+C)
// with A = bv1+bv2, B = LSE2(lv1+bv2, shr1(bv1)+lv2), C = shr1(lv1)+lv2
// built OFF the serial chain from P rows d-1, d. Serial chain per double
// step ~52cy vs ~80cy for two single steps. The on-chain validity cndmask
// is dropped: dead lanes drift (NEG-ish, finite) but are provably never
// read -- freeze-at-t=399 values are last read at the same step they would
// be destroyed (pre-update DPP read), and births self-start from NEG.
// Odd-parity dstar captured via the intermediate sub-step, computed only
// inside a wave-uniform branch (keeps steady-state trans-issue low).
// ---------------------------------------------------------------------------
__global__ __launch_bounds__(64) void k_alpha(const float2* __restrict__ pairD,
                                              const int* __restrict__ ilen,
                                              const int* __restrict__ ulenp,
                                              float* __restrict__ out) {
    const int b = blockIdx.x;
    const int u = threadIdx.x;
    const float2* Pd = pairD + (size_t)b * (DROWS_PAD * DPITCH);
    const int tl = ilen[b];
    const int ul = ulenp[b];
    const int dstar = tl - 1 + ul;
    const int dmax = ((dstar + PF - 1) / PF) * PF;   // uniform; <= 464
    const bool uok = (u <= 60);
    const bool lok = (u >= 1 && u <= 60);

    float cur = (u == 0) ? 0.f : NEGF;
    float saved = NEGF;

    float2 pf[PF];
#pragma unroll
    for (int i = 0; i < PF; ++i) pf[i] = Pd[i * DPITCH + u];

    for (int d0 = 1; d0 <= dmax; d0 += PF) {
#pragma unroll
        for (int i = 0; i < PF / 2; ++i) {
            const int d = d0 + 2 * i;                // sub-steps d, d+1
            float2 v1 = pf[2 * i];                   // row d-1
            float2 v2 = pf[2 * i + 1];               // row d
            pf[2 * i]     = Pd[(d + PF - 1) * DPITCH + u];   // row d+15 (<480)
            pf[2 * i + 1] = Pd[(d + PF)     * DPITCH + u];   // row d+16 (<480)
            const int t1 = d - u;
            const int t2 = t1 + 1;
            float bv1 = (t1 >= 1 && t1 <= 399 && uok) ? v1.x : NEGF;
            float lv1 = (lok && t1 >= 0 && t1 <= 399) ? wave_shr1(v1.y) : NEGF;
            float bv2 = (t2 >= 1 && t2 <= 399 && uok) ? v2.x : NEGF;
            float lv2 = (lok && t2 >= 0 && t2 <= 399) ? wave_shr1(v2.y) : NEGF;
            // off-chain combined weights
            float A = bv1 + bv2;
            float bv1s = wave_shr1(bv1);
            float lv1s = wave_shr1(lv1);
            float p1 = lv1 + bv2, p2 = bv1s + lv2;
            float pmx = fmaxf(p1, p2), pmn = fminf(p1, p2);
            float Bc = pmx + __log2f(1.f + __builtin_amdgcn_exp2f(pmn - pmx));
            float C = lv1s + lv2;
            // serial chain
            float sh1 = wave_shr1(cur);
            float sh2 = wave_shr1(sh1);
            float a1 = cur + A;
            float a2 = sh1 + Bc;
            float a3 = sh2 + C;
            float mx = fmaxf(fmaxf(a1, a2), a3);     // v_max3
            float s = __builtin_amdgcn_exp2f(a1 - mx)
                    + __builtin_amdgcn_exp2f(a2 - mx)
                    + __builtin_amdgcn_exp2f(a3 - mx);
            float nv = mx + __log2f(s);
            // capture (wave-uniform branch, taken once per batch)
            if ((unsigned)(dstar - d) <= 1u) {
                float xa = cur + bv1;                // intermediate sub-step d
                float xb = sh1 + lv1;
                float xmx = fmaxf(xa, xb), xmn = fminf(xa, xb);
                float x = xmx + __log2f(1.f + __builtin_amdgcn_exp2f(xmn - xmx));
                saved = (d == dstar) ? x : nv;
            }
            cur = nv;
        }
    }
    if (u == ul) out[b] = -(saved + Pd[dstar * DPITCH + u].x) * LN2F;
}

// ---------------------------------------------------------------------------
extern "C" void kernel_launch(void* const* d_in, const int* in_sizes, int n_in,
                              void* d_out, int out_size, void* d_ws, size_t ws_size,
                              hipStream_t stream) {
    const float* enc = (const float*)d_in[0];
    const float* dec = (const float*)d_in[1];
    const float* We  = (const float*)d_in[2];
    const float* Wd  = (const float*)d_in[3];
    const float* bf  = (const float*)d_in[4];
    const float* Wp  = (const float*)d_in[5];
    const float* bp  = (const float*)d_in[6];
    const int* targets = (const int*)d_in[7];
    const int* ilen    = (const int*)d_in[8];
    const int* ulen    = (const int*)d_in[9];
    float* out = (float*)d_out;
    float* ws = (float*)d_ws;

    float* f     = ws;                                        // 1,638,400 f
    float* g     = ws + 1638400;                              //   249,856 f
    unsigned short* BfragP = (unsigned short*)(ws + 1888256); //  16,384 u16
    unsigned short* WeFrag = (unsigned short*)(ws + 1896448); // 131,072 u16
    unsigned short* WdFrag = (unsigned short*)(ws + 1961984); // 131,072 u16
    float* csbp  = ws + 2027520;                              //        32 f
    float2* pairD = (float2*)(ws + 2027552);                  // 8*480*64 float2

    k_pack<<<137, 256, 0, stream>>>(We, Wd, Wp, bp, WeFrag, WdFrag, BfragP, csbp);

    k_gemm<<<462, dim3(64, 4, 1), 0, stream>>>(enc, dec, bf, WeFrag, WdFrag, f, g);

    dim3 gridC(25, 4, 8);
    dim3 blockC(64, 4, 1);
    k_cells<<<gridC, blockC, 0, stream>>>(f, g, BfragP, csbp, targets, ilen, ulen, pairD);

    k_alpha<<<8, 64, 0, stream>>>(pairD, ilen, ulen, out);
}

// Round 5
// 150.730 us; speedup vs baseline: 1.0985x; 1.0985x over previous
//
#include <hip/hip_runtime.h>
#include <hip/hip_bf16.h>
#include <math.h>

#define NEGF (-1e30f)
#define LOG2E 1.4426950408889634f
#define LN2F 0.6931471805599453f
#define TSCALE 2.885390081777927f     // 2*log2(e), folded into f and g

typedef __attribute__((ext_vector_type(8))) short bf16x8;
typedef __attribute__((ext_vector_type(4))) float f32x4;

#define DROWS_PAD 480        // diagonals 0..459 used; padded (NCH*48 <= 480)
#define DPITCH 64
#define CH 48                // alpha chunk: 48 rows = 24 KB LDS per buffer

__device__ __forceinline__ unsigned short f2bf(float x) {
    __hip_bfloat16 h = __float2bfloat16(x);
    return *reinterpret_cast<unsigned short*>(&h);
}

__device__ __forceinline__ float wave_shr1(float x) {
    int i = __builtin_bit_cast(int, x);
    int r = __builtin_amdgcn_update_dpp(0, i, 0x138, 0xf, 0xf, true); // wf_shr:1
    return __builtin_bit_cast(float, r);
}

// reciprocal via bit-hack + 1 Newton step: pure VALU (no trans pipe).
__device__ __forceinline__ float4 rcp4_nr(float4 d) {
    float4 y;
    y.x = __builtin_bit_cast(float, 0x7EF311C3 - __builtin_bit_cast(int, d.x));
    y.y = __builtin_bit_cast(float, 0x7EF311C3 - __builtin_bit_cast(int, d.y));
    y.z = __builtin_bit_cast(float, 0x7EF311C3 - __builtin_bit_cast(int, d.z));
    y.w = __builtin_bit_cast(float, 0x7EF311C3 - __builtin_bit_cast(int, d.w));
    float4 t;
    t.x = fmaf(-d.x, y.x, 2.f); t.y = fmaf(-d.y, y.y, 2.f);
    t.z = fmaf(-d.z, y.z, 2.f); t.w = fmaf(-d.w, y.w, 2.f);
    y.x *= t.x; y.y *= t.y; y.z *= t.z; y.w *= t.w;
    return y;
}

// ---------------------------------------------------------------------------
// Kernel 0 (pack): bf16 B-fragments for We (16384 entries), Wd (16384),
// and -2*Wp (2048, sigmoid form); plus csbp[v] = colsum(Wp)[v] + bp[v].
// ---------------------------------------------------------------------------
__global__ __launch_bounds__(256) void k_pack(const float* __restrict__ We,
                                              const float* __restrict__ Wd,
                                              const float* __restrict__ Wp,
                                              const float* __restrict__ bp,
                                              unsigned short* __restrict__ WeFrag,
                                              unsigned short* __restrict__ WdFrag,
                                              unsigned short* __restrict__ BfragP,
                                              float* __restrict__ csbp) {
    int gid = blockIdx.x * 256 + threadIdx.x;
    if (gid < 32768) {   // We / Wd
        const float* W = (gid < 16384) ? We : Wd;
        unsigned short* F = (gid < 16384) ? WeFrag : WdFrag;
        int s = gid & 16383;
        int lane = s & 63;
        int c = (s >> 6) & 7;
        int nt = s >> 9;
        int n = nt * 16 + (lane & 15);
        int kbase = c * 32 + ((lane >> 4) & 3) * 8;
        unsigned short* dst = F + (size_t)s * 8;
#pragma unroll
        for (int j = 0; j < 8; ++j) dst[j] = f2bf(W[(size_t)(kbase + j) * 512 + n]);
    } else if (gid < 34816) {            // -2*Wp: 2048 entries
        int s = gid - 32768;
        int lane = s & 63;
        int half = (s >> 6) & 1;
        int c = s >> 7;
        int n = half * 16 + (lane & 15);
        int kbase = c * 32 + (lane >> 4) * 8;
        unsigned short* dst = BfragP + (size_t)s * 8;
#pragma unroll
        for (int j = 0; j < 8; ++j) {
            float v = (n < 28) ? (-2.f * Wp[(kbase + j) * 28 + n]) : 0.f;
            dst[j] = f2bf(v);
        }
    } else if (gid < 34848) {            // csbp: 32 entries
        int v = gid - 34816;
        float s = 0.f;
        if (v < 28) {
            for (int k = 0; k < 512; ++k) s += Wp[k * 28 + v];
            s += bp[v];
        }
        csbp[v] = s;
    }
}

// ---------------------------------------------------------------------------
// Kernel 1 (MFMA projections): f = (enc@We)*TSCALE, g = (dec@Wd + bf)*TSCALE.
// ---------------------------------------------------------------------------
__global__ __launch_bounds__(256) void k_gemm(const float* __restrict__ enc,
                                              const float* __restrict__ dec,
                                              const float* __restrict__ bfv,
                                              const unsigned short* __restrict__ WeFrag,
                                              const unsigned short* __restrict__ WdFrag,
                                              float* __restrict__ f,
                                              float* __restrict__ g) {
    const int wid = blockIdx.x * 4 + threadIdx.y;
    const int lane = threadIdx.x;
    const int m16 = lane & 15;
    const int quad = lane >> 4;

    const float* A; const unsigned short* WF; float* Out; int M, rt, ct; bool isg;
    if (wid < 1600) { A = enc; WF = WeFrag; Out = f; M = 3200; rt = wid >> 3; ct = wid & 7; isg = false; }
    else { int w2 = wid - 1600; A = dec; WF = WdFrag; Out = g; M = 488; rt = w2 >> 3; ct = w2 & 7; isg = true; }

    const int row = rt * 16 + m16;
    const float* arow = A + (size_t)min(row, M - 1) * 256 + quad * 8;

    f32x4 acc[4];
#pragma unroll
    for (int i = 0; i < 4; ++i) acc[i] = (f32x4){0.f, 0.f, 0.f, 0.f};

#pragma unroll
    for (int c = 0; c < 8; ++c) {
        float4 a0 = *(const float4*)(arow + c * 32);
        float4 a1 = *(const float4*)(arow + c * 32 + 4);
        union { unsigned short s[8]; bf16x8 v; } Af;
        Af.s[0] = f2bf(a0.x); Af.s[1] = f2bf(a0.y);
        Af.s[2] = f2bf(a0.z); Af.s[3] = f2bf(a0.w);
        Af.s[4] = f2bf(a1.x); Af.s[5] = f2bf(a1.y);
        Af.s[6] = f2bf(a1.z); Af.s[7] = f2bf(a1.w);
#pragma unroll
        for (int i = 0; i < 4; ++i) {
            int nt = ct * 4 + i;
            bf16x8 Bv = *(const bf16x8*)(WF + (size_t)((nt * 8 + c) * 64 + lane) * 8);
            acc[i] = __builtin_amdgcn_mfma_f32_16x16x32_bf16(Af.v, Bv, acc[i], 0, 0, 0);
        }
    }

#pragma unroll
    for (int i = 0; i < 4; ++i) {
        int n = ct * 64 + i * 16 + m16;
        float bv = isg ? bfv[n] : 0.f;
#pragma unroll
        for (int r = 0; r < 4; ++r) {
            int ro = rt * 16 + quad * 4 + r;
            if (ro < M) Out[(size_t)ro * 512 + n] = (acc[i][r] + bv) * TSCALE;
        }
    }
}

// ---------------------------------------------------------------------------
// Kernel 2: per-cell blank/label log-probs (log2 domain).
// Each block stages the 16-row f tile ONCE and serves a u-span of 16
// (4 u-blocks iterated in-register): staging traffic / barrier count /4.
// Depth-1 register double-buffer pipeline per u-iteration (round-3 verified).
// ---------------------------------------------------------------------------
__global__ __launch_bounds__(256, 4) void k_cells(const float* __restrict__ f,
                                                  const float* __restrict__ g,
                                                  const unsigned short* __restrict__ Bfrag,
                                                  const float* __restrict__ csbp,
                                                  const int* __restrict__ targets,
                                                  const int* __restrict__ ilen,
                                                  const int* __restrict__ ulenp,
                                                  float2* __restrict__ pairD) {
    const int b = blockIdx.z;
    const int tlen = ilen[b];
    const int ulen = ulenp[b];
    const int t0 = blockIdx.x * 16;
    if (t0 >= tlen) return;                       // block-uniform exit
    if ((int)blockIdx.y * 16 > ulen) return;      // u-span entirely past ulen
    const int wave = threadIdx.y;
    const int lane = threadIdx.x;
    const int tid = wave * 64 + lane;

    __shared__ float fs[16 * 516];                // stride 516: b128 reads conflict-free

    {   // stage f tile (16 rows x 512), coalesced float4 -- once per block
        const float4* src = (const float4*)(f + (size_t)(b * 400 + t0) * 512);
#pragma unroll
        for (int i = 0; i < 8; ++i) {
            int idx = tid + i * 256;
            int row = idx >> 7;
            int c4 = idx & 127;
            float4 v = src[idx];
            *(float4*)&fs[row * 516 + c4 * 4] = v;
        }
    }
    __syncthreads();

    const int quad = lane >> 4;
    const int m16 = lane & 15;
    const float* fsrow = fs + m16 * 516 + quad * 8;
    const float4 one4 = make_float4(1.f, 1.f, 1.f, 1.f);
    const float cs0 = csbp[m16];
    const int n1 = 16 + m16;
    const bool n1v = (n1 < 28);
    const float cs1 = csbp[n1 & 31];
    float2* Pd = pairD + (size_t)b * (DROWS_PAD * DPITCH);

    for (int ub = 0; ub < 4; ++ub) {
        const int ubase = blockIdx.y * 16 + ub * 4;
        if (ubase > ulen) break;                  // uniform: later u never feeds answer
        const int u_raw = ubase + wave;
        const int u = min(u_raw, 60);
        const float* gu = g + (size_t)(b * 61 + u) * 512 + quad * 8;

        f32x4 acc0 = {0.f, 0.f, 0.f, 0.f};
        f32x4 acc1 = {0.f, 0.f, 0.f, 0.f};

        // depth-1 software pipeline: load iteration c+1 while computing c.
        float4 FA[2], FB[2], GA[2], GB[2];
        bf16x8 BR0[2], BR1[2];
        FA[0] = *(const float4*)(fsrow);
        FB[0] = *(const float4*)(fsrow + 4);
        GA[0] = *(const float4*)(gu);
        GB[0] = *(const float4*)(gu + 4);
        BR0[0] = *(const bf16x8*)(Bfrag + ((size_t)(0 * 64 + lane)) * 8);
        BR1[0] = *(const bf16x8*)(Bfrag + ((size_t)(1 * 64 + lane)) * 8);

#pragma unroll
        for (int c = 0; c < 16; ++c) {
            const int cu = c & 1;            // static after full unroll
            const int nx = cu ^ 1;
            if (c < 15) {
                FA[nx] = *(const float4*)(fsrow + (c + 1) * 32);
                FB[nx] = *(const float4*)(fsrow + (c + 1) * 32 + 4);
                GA[nx] = *(const float4*)(gu + (c + 1) * 32);
                GB[nx] = *(const float4*)(gu + (c + 1) * 32 + 4);
                BR0[nx] = *(const bf16x8*)(Bfrag + ((size_t)(((c + 1) * 2 + 0) * 64 + lane)) * 8);
                BR1[nx] = *(const bf16x8*)(Bfrag + ((size_t)(((c + 1) * 2 + 1) * 64 + lane)) * 8);
            }
            float4 s0 = FA[cu] + GA[cu];              // pk adds (pre-scaled by 2log2e)
            float4 s1 = FB[cu] + GB[cu];
            float4 e0, e1;
            e0.x = __builtin_amdgcn_exp2f(s0.x); e0.y = __builtin_amdgcn_exp2f(s0.y);
            e0.z = __builtin_amdgcn_exp2f(s0.z); e0.w = __builtin_amdgcn_exp2f(s0.w);
            e1.x = __builtin_amdgcn_exp2f(s1.x); e1.y = __builtin_amdgcn_exp2f(s1.y);
            e1.z = __builtin_amdgcn_exp2f(s1.z); e1.w = __builtin_amdgcn_exp2f(s1.w);
            float4 r0 = rcp4_nr(e0 + one4);           // sigma = 1/(1+e), no trans rcp
            float4 r1 = rcp4_nr(e1 + one4);
            union { unsigned short s[8]; bf16x8 v; } A;
            A.s[0] = f2bf(r0.x); A.s[1] = f2bf(r0.y);
            A.s[2] = f2bf(r0.z); A.s[3] = f2bf(r0.w);
            A.s[4] = f2bf(r1.x); A.s[5] = f2bf(r1.y);
            A.s[6] = f2bf(r1.z); A.s[7] = f2bf(r1.w);
            acc0 = __builtin_amdgcn_mfma_f32_16x16x32_bf16(A.v, BR0[cu], acc0, 0, 0, 0);
            acc1 = __builtin_amdgcn_mfma_f32_16x16x32_bf16(A.v, BR1[cu], acc1, 0, 0, 0);
        }

        // epilogue: logits l[v] = csbp[v] + acc  (acc = sum(-2Wp * sigma))
        int tv = targets[b * 60 + min(u, 59)];

        float res_blank[4], res_lab[4];
#pragma unroll
        for (int r = 0; r < 4; ++r) {
            float l0 = acc0[r] + cs0;
            float l1 = n1v ? (acc1[r] + cs1) : NEGF;
            float mx = fmaxf(l0, l1);
            mx = fmaxf(mx, __shfl_xor(mx, 1, 64));
            mx = fmaxf(mx, __shfl_xor(mx, 2, 64));
            mx = fmaxf(mx, __shfl_xor(mx, 4, 64));
            mx = fmaxf(mx, __shfl_xor(mx, 8, 64));
            float s = __builtin_amdgcn_exp2f((l0 - mx) * LOG2E) +
                      __builtin_amdgcn_exp2f((l1 - mx) * LOG2E);
            s += __shfl_xor(s, 1, 64);
            s += __shfl_xor(s, 2, 64);
            s += __shfl_xor(s, 4, 64);
            s += __shfl_xor(s, 8, 64);
            float lse = mx + __logf(s);
            int base = lane & 48;
            float labsrc = (tv < 16) ? l0 : l1;
            float labv = __shfl(labsrc, base | (tv & 15), 64);
            float blankv = __shfl(l1, base | 11, 64);   // v=27 -> half1 local 11
            res_blank[r] = (blankv - lse) * LOG2E;      // log2 domain
            res_lab[r] = (labv - lse) * LOG2E;
        }

        if (m16 == 0 && u_raw <= 60) {
#pragma unroll
            for (int r = 0; r < 4; ++r) {
                int t = t0 + quad * 4 + r;
                if (t < tlen) {
                    int d = t + u;
                    float2 pr;
                    pr.x = res_blank[r];
                    pr.y = (u <= 59) ? res_lab[r] : NEGF;
                    Pd[d * DPITCH + u] = pr;
                }
            }
        }
    }
}

// ---------------------------------------------------------------------------
// Kernel 3: anti-diagonal alpha recursion, producer-consumer.
// One 256-thread block per batch. Waves 1-3 stream pairD chunk k+1 (48 rows,
// 24 KB) into double-buffered LDS while wave 0 runs the serial chain on
// chunk k from LDS (ds_read ~120cy, hidden inside the 48-row chain). One
// barrier per chunk. The chain math/op-order is VERBATIM the round-2
// verified single-step version (absmax 0.0 twice) -- only the data source
// moved from high-latency global prefetch to LDS.
// ---------------------------------------------------------------------------
__global__ __launch_bounds__(256) void k_alpha(const float2* __restrict__ pairD,
                                               const int* __restrict__ ilen,
                                               const int* __restrict__ ulenp,
                                               float* __restrict__ out) {
    const int b = blockIdx.x;
    const int u = threadIdx.x;
    const int w = threadIdx.y;
    const float2* Pd = pairD + (size_t)b * (DROWS_PAD * DPITCH);
    const int tl = ilen[b];
    const int ul = ulenp[b];
    const int dstar = tl - 1 + ul;
    const int NCH = (dstar + CH - 1) / CH;       // <= 10; rows < NCH*CH <= 480
    const bool uok = (u <= 60);
    const bool lok = (u >= 1 && u <= 60);

    __shared__ char lbuf[2 * CH * 512];          // 48 KiB: 2 x 48 rows x 512 B

    {   // prologue: all 4 waves copy chunk 0 into buffer 0 (1536 float4)
        const int tid = w * 64 + u;
        const float4* gs = (const float4*)Pd;
        float4* ld = (float4*)lbuf;
#pragma unroll
        for (int j = 0; j < 6; ++j) ld[tid + j * 256] = gs[tid + j * 256];
    }
    __syncthreads();

    float cur = (u == 0) ? 0.f : NEGF;
    float saved = NEGF, savedBlank = NEGF;

    for (int k = 0; k < NCH; ++k) {
        if (w > 0 && (k + 1) < NCH) {            // producers: copy chunk k+1
            const int pt = (w - 1) * 64 + u;     // 0..191
            const float4* gs = (const float4*)(Pd + (size_t)(k + 1) * CH * DPITCH);
            float4* ld = (float4*)(lbuf + ((k + 1) & 1) * (CH * 512));
#pragma unroll
            for (int j = 0; j < 8; ++j)          // 192*8 = 1536 float4
                ld[pt + j * 192] = gs[pt + j * 192];
        }
        if (w == 0) {                            // consumer: chain over chunk k
            const char* base = lbuf + (k & 1) * (CH * 512);
            const int d0 = k * CH + 1;
#pragma unroll 16
            for (int r = 0; r < CH; ++r) {
                const int d = d0 + r;
                float2 v = *(const float2*)(base + r * 512 + u * 8);
                int t = d - u;
                float bv = (t >= 1 && t <= 399 && uok) ? v.x : NEGF;
                float lvn = wave_shr1(v.y);
                float lv = (lok && t >= 0 && t <= 399) ? lvn : NEGF;
                float up = wave_shr1(cur);
                float a = cur + bv;
                float c2 = up + lv;
                float mx = fmaxf(a, c2), mn = fminf(a, c2);
                float nv = mx + __log2f(1.f + __builtin_amdgcn_exp2f(mn - mx));
                bool valid = (t >= 0 && t <= 399 && uok);
                cur = valid ? nv : cur;
                saved = (d == dstar) ? cur : saved;
                savedBlank = (d == dstar) ? v.x : savedBlank;
            }
        }
        __syncthreads();
    }
    if (w == 0 && u == ul) out[b] = -(saved + savedBlank) * LN2F;
}

// ---------------------------------------------------------------------------
extern "C" void kernel_launch(void* const* d_in, const int* in_sizes, int n_in,
                              void* d_out, int out_size, void* d_ws, size_t ws_size,
                              hipStream_t stream) {
    const float* enc = (const float*)d_in[0];
    const float* dec = (const float*)d_in[1];
    const float* We  = (const float*)d_in[2];
    const float* Wd  = (const float*)d_in[3];
    const float* bf  = (const float*)d_in[4];
    const float* Wp  = (const float*)d_in[5];
    const float* bp  = (const float*)d_in[6];
    const int* targets = (const int*)d_in[7];
    const int* ilen    = (const int*)d_in[8];
    const int* ulen    = (const int*)d_in[9];
    float* out = (float*)d_out;
    float* ws = (float*)d_ws;

    float* f     = ws;                                        // 1,638,400 f
    float* g     = ws + 1638400;                              //   249,856 f
    unsigned short* BfragP = (unsigned short*)(ws + 1888256); //  16,384 u16
    unsigned short* WeFrag = (unsigned short*)(ws + 1896448); // 131,072 u16
    unsigned short* WdFrag = (unsigned short*)(ws + 1961984); // 131,072 u16
    float* csbp  = ws + 2027520;                              //        32 f
    float2* pairD = (float2*)(ws + 2027552);                  // 8*480*64 float2

    k_pack<<<137, 256, 0, stream>>>(We, Wd, Wp, bp, WeFrag, WdFrag, BfragP, csbp);

    k_gemm<<<462, dim3(64, 4, 1), 0, stream>>>(enc, dec, bf, WeFrag, WdFrag, f, g);

    dim3 gridC(25, 4, 8);
    dim3 blockC(64, 4, 1);
    k_cells<<<gridC, blockC, 0, stream>>>(f, g, BfragP, csbp, targets, ilen, ulen, pairD);

    k_alpha<<<8, dim3(64, 4, 1), 0, stream>>>(pairD, ilen, ulen, out);
}

// Round 6
// 142.567 us; speedup vs baseline: 1.1614x; 1.0573x over previous
//
#include <hip/hip_runtime.h>
#include <hip/hip_bf16.h>
#include <math.h>

#define NEGF (-1e30f)
#define LOG2E 1.4426950408889634f
#define LN2F 0.6931471805599453f
#define TSCALE 2.885390081777927f     // 2*log2(e), folded into f and g

typedef __attribute__((ext_vector_type(8))) short bf16x8;
typedef __attribute__((ext_vector_type(4))) float f32x4;

#define DROWS_PAD 480        // diagonals 0..459 used; padded (NCH*48 <= 480)
#define DPITCH 64
#define CH 48                // alpha chunk: 48 rows = 24 KB LDS per buffer

__device__ __forceinline__ unsigned short f2bf(float x) {
    __hip_bfloat16 h = __float2bfloat16(x);
    return *reinterpret_cast<unsigned short*>(&h);
}

__device__ __forceinline__ float wave_shr1(float x) {
    int i = __builtin_bit_cast(int, x);
    int r = __builtin_amdgcn_update_dpp(0, i, 0x138, 0xf, 0xf, true); // wf_shr:1
    return __builtin_bit_cast(float, r);
}

// reciprocal via bit-hack + 1 Newton step: pure VALU (no trans pipe).
__device__ __forceinline__ float4 rcp4_nr(float4 d) {
    float4 y;
    y.x = __builtin_bit_cast(float, 0x7EF311C3 - __builtin_bit_cast(int, d.x));
    y.y = __builtin_bit_cast(float, 0x7EF311C3 - __builtin_bit_cast(int, d.y));
    y.z = __builtin_bit_cast(float, 0x7EF311C3 - __builtin_bit_cast(int, d.z));
    y.w = __builtin_bit_cast(float, 0x7EF311C3 - __builtin_bit_cast(int, d.w));
    float4 t;
    t.x = fmaf(-d.x, y.x, 2.f); t.y = fmaf(-d.y, y.y, 2.f);
    t.z = fmaf(-d.z, y.z, 2.f); t.w = fmaf(-d.w, y.w, 2.f);
    y.x *= t.x; y.y *= t.y; y.z *= t.z; y.w *= t.w;
    return y;
}

// ---------------------------------------------------------------------------
// Kernel 0 (pack): bf16 B-fragments for We (16384 entries), Wd (16384),
// and -2*Wp (2048, sigmoid form); plus csbp[v] = colsum(Wp)[v] + bp[v].
// ---------------------------------------------------------------------------
__global__ __launch_bounds__(256) void k_pack(const float* __restrict__ We,
                                              const float* __restrict__ Wd,
                                              const float* __restrict__ Wp,
                                              const float* __restrict__ bp,
                                              unsigned short* __restrict__ WeFrag,
                                              unsigned short* __restrict__ WdFrag,
                                              unsigned short* __restrict__ BfragP,
                                              float* __restrict__ csbp) {
    int gid = blockIdx.x * 256 + threadIdx.x;
    if (gid < 32768) {   // We / Wd
        const float* W = (gid < 16384) ? We : Wd;
        unsigned short* F = (gid < 16384) ? WeFrag : WdFrag;
        int s = gid & 16383;
        int lane = s & 63;
        int c = (s >> 6) & 7;
        int nt = s >> 9;
        int n = nt * 16 + (lane & 15);
        int kbase = c * 32 + ((lane >> 4) & 3) * 8;
        unsigned short* dst = F + (size_t)s * 8;
#pragma unroll
        for (int j = 0; j < 8; ++j) dst[j] = f2bf(W[(size_t)(kbase + j) * 512 + n]);
    } else if (gid < 34816) {            // -2*Wp: 2048 entries
        int s = gid - 32768;
        int lane = s & 63;
        int half = (s >> 6) & 1;
        int c = s >> 7;
        int n = half * 16 + (lane & 15);
        int kbase = c * 32 + (lane >> 4) * 8;
        unsigned short* dst = BfragP + (size_t)s * 8;
#pragma unroll
        for (int j = 0; j < 8; ++j) {
            float v = (n < 28) ? (-2.f * Wp[(kbase + j) * 28 + n]) : 0.f;
            dst[j] = f2bf(v);
        }
    } else if (gid < 34848) {            // csbp: 32 entries
        int v = gid - 34816;
        float s = 0.f;
        if (v < 28) {
            for (int k = 0; k < 512; ++k) s += Wp[k * 28 + v];
            s += bp[v];
        }
        csbp[v] = s;
    }
}

// ---------------------------------------------------------------------------
// Kernel 1 (MFMA projections): f = (enc@We)*TSCALE, g = (dec@Wd + bf)*TSCALE.
// ---------------------------------------------------------------------------
__global__ __launch_bounds__(256) void k_gemm(const float* __restrict__ enc,
                                              const float* __restrict__ dec,
                                              const float* __restrict__ bfv,
                                              const unsigned short* __restrict__ WeFrag,
                                              const unsigned short* __restrict__ WdFrag,
                                              float* __restrict__ f,
                                              float* __restrict__ g) {
    const int wid = blockIdx.x * 4 + threadIdx.y;
    const int lane = threadIdx.x;
    const int m16 = lane & 15;
    const int quad = lane >> 4;

    const float* A; const unsigned short* WF; float* Out; int M, rt, ct; bool isg;
    if (wid < 1600) { A = enc; WF = WeFrag; Out = f; M = 3200; rt = wid >> 3; ct = wid & 7; isg = false; }
    else { int w2 = wid - 1600; A = dec; WF = WdFrag; Out = g; M = 488; rt = w2 >> 3; ct = w2 & 7; isg = true; }

    const int row = rt * 16 + m16;
    const float* arow = A + (size_t)min(row, M - 1) * 256 + quad * 8;

    f32x4 acc[4];
#pragma unroll
    for (int i = 0; i < 4; ++i) acc[i] = (f32x4){0.f, 0.f, 0.f, 0.f};

#pragma unroll
    for (int c = 0; c < 8; ++c) {
        float4 a0 = *(const float4*)(arow + c * 32);
        float4 a1 = *(const float4*)(arow + c * 32 + 4);
        union { unsigned short s[8]; bf16x8 v; } Af;
        Af.s[0] = f2bf(a0.x); Af.s[1] = f2bf(a0.y);
        Af.s[2] = f2bf(a0.z); Af.s[3] = f2bf(a0.w);
        Af.s[4] = f2bf(a1.x); Af.s[5] = f2bf(a1.y);
        Af.s[6] = f2bf(a1.z); Af.s[7] = f2bf(a1.w);
#pragma unroll
        for (int i = 0; i < 4; ++i) {
            int nt = ct * 4 + i;
            bf16x8 Bv = *(const bf16x8*)(WF + (size_t)((nt * 8 + c) * 64 + lane) * 8);
            acc[i] = __builtin_amdgcn_mfma_f32_16x16x32_bf16(Af.v, Bv, acc[i], 0, 0, 0);
        }
    }

#pragma unroll
    for (int i = 0; i < 4; ++i) {
        int n = ct * 64 + i * 16 + m16;
        float bv = isg ? bfv[n] : 0.f;
#pragma unroll
        for (int r = 0; r < 4; ++r) {
            int ro = rt * 16 + quad * 4 + r;
            if (ro < M) Out[(size_t)ro * 512 + n] = (acc[i][r] + bv) * TSCALE;
        }
    }
}

// ---------------------------------------------------------------------------
// Kernel 2: per-cell blank/label log-probs (log2 domain).
// 8-wave blocks, ONE u per wave: the f tile is staged once and shared by
// 8 u-values (vs 4 in r3, at IDENTICAL wave-level parallelism: 16 waves/CU
// under the 128-VGPR cap). r5's u-span-16 variant cut global parallelism
// 4x and regressed; this keeps ~7800 waves while halving staging traffic.
// Per-wave body is the round-3-verified depth-1 double-buffer pipeline.
// ---------------------------------------------------------------------------
__global__ __launch_bounds__(512, 4) void k_cells(const float* __restrict__ f,
                                                  const float* __restrict__ g,
                                                  const unsigned short* __restrict__ Bfrag,
                                                  const float* __restrict__ csbp,
                                                  const int* __restrict__ targets,
                                                  const int* __restrict__ ilen,
                                                  const int* __restrict__ ulenp,
                                                  float2* __restrict__ pairD) {
    const int b = blockIdx.z;
    const int tlen = ilen[b];
    const int ulen = ulenp[b];
    const int t0 = blockIdx.x * 16;
    if (t0 >= tlen) return;                       // block-uniform exit
    if ((int)blockIdx.y * 8 > ulen) return;       // u-oct entirely past ulen
    const int wave = threadIdx.y;
    const int lane = threadIdx.x;
    const int tid = wave * 64 + lane;

    __shared__ float fs[16 * 516];                // stride 516: b128 reads conflict-free

    {   // stage f tile (16 rows x 512), coalesced float4 -- once per 8 u
        const float4* src = (const float4*)(f + (size_t)(b * 400 + t0) * 512);
#pragma unroll
        for (int i = 0; i < 4; ++i) {
            int idx = tid + i * 512;
            int row = idx >> 7;
            int c4 = idx & 127;
            float4 v = src[idx];
            *(float4*)&fs[row * 516 + c4 * 4] = v;
        }
    }
    __syncthreads();

    const int quad = lane >> 4;
    const int m16 = lane & 15;
    const int u_raw = blockIdx.y * 8 + wave;
    const int u = min(u_raw, 60);
    const float* fsrow = fs + m16 * 516 + quad * 8;
    const float* gu = g + (size_t)(b * 61 + u) * 512 + quad * 8;
    const float4 one4 = make_float4(1.f, 1.f, 1.f, 1.f);

    f32x4 acc0 = {0.f, 0.f, 0.f, 0.f};
    f32x4 acc1 = {0.f, 0.f, 0.f, 0.f};

    // depth-1 software pipeline: load iteration c+1 while computing c.
    float4 FA[2], FB[2], GA[2], GB[2];
    bf16x8 BR0[2], BR1[2];
    FA[0] = *(const float4*)(fsrow);
    FB[0] = *(const float4*)(fsrow + 4);
    GA[0] = *(const float4*)(gu);
    GB[0] = *(const float4*)(gu + 4);
    BR0[0] = *(const bf16x8*)(Bfrag + ((size_t)(0 * 64 + lane)) * 8);
    BR1[0] = *(const bf16x8*)(Bfrag + ((size_t)(1 * 64 + lane)) * 8);

#pragma unroll
    for (int c = 0; c < 16; ++c) {
        const int cu = c & 1;            // static after full unroll
        const int nx = cu ^ 1;
        if (c < 15) {
            FA[nx] = *(const float4*)(fsrow + (c + 1) * 32);
            FB[nx] = *(const float4*)(fsrow + (c + 1) * 32 + 4);
            GA[nx] = *(const float4*)(gu + (c + 1) * 32);
            GB[nx] = *(const float4*)(gu + (c + 1) * 32 + 4);
            BR0[nx] = *(const bf16x8*)(Bfrag + ((size_t)(((c + 1) * 2 + 0) * 64 + lane)) * 8);
            BR1[nx] = *(const bf16x8*)(Bfrag + ((size_t)(((c + 1) * 2 + 1) * 64 + lane)) * 8);
        }
        float4 s0 = FA[cu] + GA[cu];              // pk adds (pre-scaled by 2log2e)
        float4 s1 = FB[cu] + GB[cu];
        float4 e0, e1;
        e0.x = __builtin_amdgcn_exp2f(s0.x); e0.y = __builtin_amdgcn_exp2f(s0.y);
        e0.z = __builtin_amdgcn_exp2f(s0.z); e0.w = __builtin_amdgcn_exp2f(s0.w);
        e1.x = __builtin_amdgcn_exp2f(s1.x); e1.y = __builtin_amdgcn_exp2f(s1.y);
        e1.z = __builtin_amdgcn_exp2f(s1.z); e1.w = __builtin_amdgcn_exp2f(s1.w);
        float4 r0 = rcp4_nr(e0 + one4);           // sigma = 1/(1+e), no trans rcp
        float4 r1 = rcp4_nr(e1 + one4);
        union { unsigned short s[8]; bf16x8 v; } A;
        A.s[0] = f2bf(r0.x); A.s[1] = f2bf(r0.y);
        A.s[2] = f2bf(r0.z); A.s[3] = f2bf(r0.w);
        A.s[4] = f2bf(r1.x); A.s[5] = f2bf(r1.y);
        A.s[6] = f2bf(r1.z); A.s[7] = f2bf(r1.w);
        acc0 = __builtin_amdgcn_mfma_f32_16x16x32_bf16(A.v, BR0[cu], acc0, 0, 0, 0);
        acc1 = __builtin_amdgcn_mfma_f32_16x16x32_bf16(A.v, BR1[cu], acc1, 0, 0, 0);
    }

    // epilogue: logits l[v] = csbp[v] + acc  (acc = sum(-2Wp * sigma))
    const float cs0 = csbp[m16];
    const int n1 = 16 + m16;
    const bool n1v = (n1 < 28);
    const float cs1 = csbp[n1 & 31];
    int tv = targets[b * 60 + min(u, 59)];

    float res_blank[4], res_lab[4];
#pragma unroll
    for (int r = 0; r < 4; ++r) {
        float l0 = acc0[r] + cs0;
        float l1 = n1v ? (acc1[r] + cs1) : NEGF;
        float mx = fmaxf(l0, l1);
        mx = fmaxf(mx, __shfl_xor(mx, 1, 64));
        mx = fmaxf(mx, __shfl_xor(mx, 2, 64));
        mx = fmaxf(mx, __shfl_xor(mx, 4, 64));
        mx = fmaxf(mx, __shfl_xor(mx, 8, 64));
        float s = __builtin_amdgcn_exp2f((l0 - mx) * LOG2E) +
                  __builtin_amdgcn_exp2f((l1 - mx) * LOG2E);
        s += __shfl_xor(s, 1, 64);
        s += __shfl_xor(s, 2, 64);
        s += __shfl_xor(s, 4, 64);
        s += __shfl_xor(s, 8, 64);
        float lse = mx + __logf(s);
        int base = lane & 48;
        float labsrc = (tv < 16) ? l0 : l1;
        float labv = __shfl(labsrc, base | (tv & 15), 64);
        float blankv = __shfl(l1, base | 11, 64);   // v=27 -> half1 local 11
        res_blank[r] = (blankv - lse) * LOG2E;      // log2 domain
        res_lab[r] = (labv - lse) * LOG2E;
    }

    if (m16 == 0 && u_raw <= 60) {
        float2* Pd = pairD + (size_t)b * (DROWS_PAD * DPITCH);
#pragma unroll
        for (int r = 0; r < 4; ++r) {
            int t = t0 + quad * 4 + r;
            if (t < tlen) {
                int d = t + u;
                float2 pr;
                pr.x = res_blank[r];
                pr.y = (u <= 59) ? res_lab[r] : NEGF;
                Pd[d * DPITCH + u] = pr;
            }
        }
    }
}

// ---------------------------------------------------------------------------
// Kernel 3: anti-diagonal alpha recursion, producer-consumer (r5-verified).
// Waves 1-3 stream pairD chunk k+1 (48 rows, 24 KB) into double-buffered LDS
// while wave 0 runs the verbatim r2 chain on chunk k from LDS.
// ---------------------------------------------------------------------------
__global__ __launch_bounds__(256) void k_alpha(const float2* __restrict__ pairD,
                                               const int* __restrict__ ilen,
                                               const int* __restrict__ ulenp,
                                               float* __restrict__ out) {
    const int b = blockIdx.x;
    const int u = threadIdx.x;
    const int w = threadIdx.y;
    const float2* Pd = pairD + (size_t)b * (DROWS_PAD * DPITCH);
    const int tl = ilen[b];
    const int ul = ulenp[b];
    const int dstar = tl - 1 + ul;
    const int NCH = (dstar + CH - 1) / CH;       // <= 10; rows < NCH*CH <= 480
    const bool uok = (u <= 60);
    const bool lok = (u >= 1 && u <= 60);

    __shared__ char lbuf[2 * CH * 512];          // 48 KiB: 2 x 48 rows x 512 B

    {   // prologue: all 4 waves copy chunk 0 into buffer 0 (1536 float4)
        const int tid = w * 64 + u;
        const float4* gs = (const float4*)Pd;
        float4* ld = (float4*)lbuf;
#pragma unroll
        for (int j = 0; j < 6; ++j) ld[tid + j * 256] = gs[tid + j * 256];
    }
    __syncthreads();

    float cur = (u == 0) ? 0.f : NEGF;
    float saved = NEGF, savedBlank = NEGF;

    for (int k = 0; k < NCH; ++k) {
        if (w > 0 && (k + 1) < NCH) {            // producers: copy chunk k+1
            const int pt = (w - 1) * 64 + u;     // 0..191
            const float4* gs = (const float4*)(Pd + (size_t)(k + 1) * CH * DPITCH);
            float4* ld = (float4*)(lbuf + ((k + 1) & 1) * (CH * 512));
#pragma unroll
            for (int j = 0; j < 8; ++j)          // 192*8 = 1536 float4
                ld[pt + j * 192] = gs[pt + j * 192];
        }
        if (w == 0) {                            // consumer: chain over chunk k
            const char* base = lbuf + (k & 1) * (CH * 512);
            const int d0 = k * CH + 1;
#pragma unroll 16
            for (int r = 0; r < CH; ++r) {
                const int d = d0 + r;
                float2 v = *(const float2*)(base + r * 512 + u * 8);
                int t = d - u;
                float bv = (t >= 1 && t <= 399 && uok) ? v.x : NEGF;
                float lvn = wave_shr1(v.y);
                float lv = (lok && t >= 0 && t <= 399) ? lvn : NEGF;
                float up = wave_shr1(cur);
                float a = cur + bv;
                float c2 = up + lv;
                float mx = fmaxf(a, c2), mn = fminf(a, c2);
                float nv = mx + __log2f(1.f + __builtin_amdgcn_exp2f(mn - mx));
                bool valid = (t >= 0 && t <= 399 && uok);
                cur = valid ? nv : cur;
                saved = (d == dstar) ? cur : saved;
                savedBlank = (d == dstar) ? v.x : savedBlank;
            }
        }
        __syncthreads();
    }
    if (w == 0 && u == ul) out[b] = -(saved + savedBlank) * LN2F;
}

// ---------------------------------------------------------------------------
extern "C" void kernel_launch(void* const* d_in, const int* in_sizes, int n_in,
                              void* d_out, int out_size, void* d_ws, size_t ws_size,
                              hipStream_t stream) {
    const float* enc = (const float*)d_in[0];
    const float* dec = (const float*)d_in[1];
    const float* We  = (const float*)d_in[2];
    const float* Wd  = (const float*)d_in[3];
    const float* bf  = (const float*)d_in[4];
    const float* Wp  = (const float*)d_in[5];
    const float* bp  = (const float*)d_in[6];
    const int* targets = (const int*)d_in[7];
    const int* ilen    = (const int*)d_in[8];
    const int* ulen    = (const int*)d_in[9];
    float* out = (float*)d_out;
    float* ws = (float*)d_ws;

    float* f     = ws;                                        // 1,638,400 f
    float* g     = ws + 1638400;                              //   249,856 f
    unsigned short* BfragP = (unsigned short*)(ws + 1888256); //  16,384 u16
    unsigned short* WeFrag = (unsigned short*)(ws + 1896448); // 131,072 u16
    unsigned short* WdFrag = (unsigned short*)(ws + 1961984); // 131,072 u16
    float* csbp  = ws + 2027520;                              //        32 f
    float2* pairD = (float2*)(ws + 2027552);                  // 8*480*64 float2

    k_pack<<<137, 256, 0, stream>>>(We, Wd, Wp, bp, WeFrag, WdFrag, BfragP, csbp);

    k_gemm<<<462, dim3(64, 4, 1), 0, stream>>>(enc, dec, bf, WeFrag, WdFrag, f, g);

    dim3 gridC(25, 8, 8);
    dim3 blockC(64, 8, 1);
    k_cells<<<gridC, blockC, 0, stream>>>(f, g, BfragP, csbp, targets, ilen, ulen, pairD);

    k_alpha<<<8, dim3(64, 4, 1), 0, stream>>>(pairD, ilen, ulen, out);
}